// Round 8
// baseline (617.811 us; speedup 1.0000x reference)
//
#include <hip/hip_runtime.h>

typedef unsigned short ushort_t;
typedef __bf16 bf16x8 __attribute__((ext_vector_type(8)));
typedef float f32x4 __attribute__((ext_vector_type(4)));
typedef unsigned u32x4 __attribute__((ext_vector_type(4)));

// ---------- workspace layout (bytes) ----------
#define WS_FLAGS   0x0        // 16 flags, 128B apart
#define WS_CTX     0x14000    // ctx [32][1024] f32
#define WS_CTXT    0x34000    // ctx_T [1024][32] f32
#define WS_CTXRD   0x54000    // ctx_read [32][512] f32
#define WS_F1      0x64000    // F1r [512][32][4] f32 (feed+bias)
#define WS_F0      0xA4000    // F0r (bias only)
#define WS_EBF     0xE4000    // E_bf16 [2048][512]   (m' = t*32+b)
#define WS_WIH     0x2E4000   // Wih' bf16 [2048][512] (j' = 4d+g order)
#define WS_WHH     0x4E4000   // Whh' bf16 [2048][512]
#define WS_C2RT    0x6E4000   // c2r_top^T bf16 [512][512]
#define WS_RT      0x764000   // readout^T bf16 [32000][512]
#define WS_EG      0x26A4000  // Eg2 bf16 [64 t][512 d][32 b][4 g]  (8 MB)
#define WS_HH      0x2EA4000  // Hh bf16 [65 ts][32 b][512 d] write-once history (2.08 MB)
#define WS_H       0x36A4000  // H bf16 [2048][512]  (m = b*64+t)
#define WS_P       0x38A4000  // P bf16 [2048][512]

__device__ __forceinline__ unsigned short f2bf(float f) {
  unsigned u = __builtin_bit_cast(unsigned, f);
  u = (u + 0x7FFFu + ((u >> 16) & 1u)) >> 16;
  return (unsigned short)u;
}
__device__ __forceinline__ float bfu2f(unsigned s) {
  return __builtin_bit_cast(float, s << 16);
}
__device__ __forceinline__ uint4 pack8(float4 a, float4 b) {
  uint4 o;
  o.x = (unsigned)f2bf(a.x) | ((unsigned)f2bf(a.y) << 16);
  o.y = (unsigned)f2bf(a.z) | ((unsigned)f2bf(a.w) << 16);
  o.z = (unsigned)f2bf(b.x) | ((unsigned)f2bf(b.y) << 16);
  o.w = (unsigned)f2bf(b.z) | ((unsigned)f2bf(b.w) << 16);
  return o;
}
__device__ __forceinline__ float sigm(float x) { return 1.0f / (1.0f + __expf(-x)); }
__device__ __forceinline__ float tanh_f(float x) {
  float a = fabsf(x);
  float t = __expf(-2.0f * a);
  float r = (1.0f - t) / (1.0f + t);
  return x < 0.0f ? -r : r;
}
__device__ __forceinline__ void gload_lds16(const void* g, void* l) {
  __builtin_amdgcn_global_load_lds((const __attribute__((address_space(1))) unsigned*)g,
                                   (__attribute__((address_space(3))) unsigned*)l, 16, 0, 0);
}
// sc1 = agent-coherent load: bypasses (misses) this XCD's L1/L2, reads LLC.
__device__ __forceinline__ void gload_lds16_sc(const void* g, void* l) {
  __builtin_amdgcn_global_load_lds((const __attribute__((address_space(1))) unsigned*)g,
                                   (__attribute__((address_space(3))) unsigned*)l, 16, 0, 16);
}

// ---------- Phase A: attention weights + ctx (step-independent) ----------
__global__ __launch_bounds__(256) void k_ctx(const float* __restrict__ xk,
                                             const float* __restrict__ xenc,
                                             const float* __restrict__ watt,
                                             float* __restrict__ ctx,
                                             float* __restrict__ ctxT) {
  const int b = blockIdx.x, tid = threadIdx.x;
  __shared__ float part[256];
  __shared__ float attw[64];
  const int lq = tid >> 2, q = tid & 3;
  const float* row = xk + ((size_t)b * 64 + lq) * 512 + q * 128;
  const float* wa = watt + q * 128;
  float s = 0.0f;
  for (int i = 0; i < 128; i += 4) {
    float4 a = *(const float4*)(row + i);
    float4 w = *(const float4*)(wa + i);
    s += a.x * w.x + a.y * w.y + a.z * w.z + a.w * w.w;
  }
  part[tid] = s;
  __syncthreads();
  if (tid < 64) {
    float sc = part[tid * 4] + part[tid * 4 + 1] + part[tid * 4 + 2] + part[tid * 4 + 3];
    float m = sc;
    for (int off = 32; off; off >>= 1) m = fmaxf(m, __shfl_xor(m, off));
    float e = __expf(sc - m);
    float ssum = e;
    for (int off = 32; off; off >>= 1) ssum += __shfl_xor(ssum, off);
    attw[tid] = e / ssum;
  }
  __syncthreads();
  for (int v = tid; v < 1024; v += 256) {
    float a = 0.0f;
    for (int L = 0; L < 64; ++L) a += attw[L] * xenc[((size_t)b * 64 + L) * 1024 + v];
    ctx[b * 1024 + v] = a;
    ctxT[v * 32 + b] = a;
  }
}

// ---------- Phase B: feed term + ctx_read ----------
__global__ __launch_bounds__(256) void k_feed(const float* __restrict__ ctxT,
                                              const float* __restrict__ W_ih,
                                              const float* __restrict__ bih,
                                              const float* __restrict__ bhh,
                                              const float* __restrict__ c2r,
                                              float* __restrict__ F1r,
                                              float* __restrict__ F0r,
                                              float* __restrict__ ctx_read) {
  const int wg = blockIdx.x, tid = threadIdx.x;
  const int b = tid & 31, sub = tid >> 5;
  if (wg < 256) {
    const int jp = wg * 8 + sub;          // j' row
    const int d = jp >> 2, g = jp & 3;
    const int j = g * 512 + d;            // original gate row
    const float* wr = W_ih + (size_t)j * 1536 + 512;
    float s = 0.0f;
    for (int v = 0; v < 1024; v += 4) {
      float4 wv = *(const float4*)(wr + v);
      s += ctxT[(v + 0) * 32 + b] * wv.x + ctxT[(v + 1) * 32 + b] * wv.y +
           ctxT[(v + 2) * 32 + b] * wv.z + ctxT[(v + 3) * 32 + b] * wv.w;
    }
    float bias = bih[j] + bhh[j];
    F1r[((d * 32) + b) * 4 + g] = s + bias;
    F0r[((d * 32) + b) * 4 + g] = bias;
  } else {
    const int n = (wg - 256) * 8 + sub;
    const float* cr = c2r + (size_t)512 * 512;  // ctx rows of ctx2read_w
    float s = 0.0f;
    for (int v = 0; v < 1024; ++v) s += ctxT[v * 32 + b] * cr[(size_t)v * 512 + n];
    ctx_read[b * 512 + n] = s;
  }
}

// ---------- Phase C: converts / gathers ----------
__global__ __launch_bounds__(64) void k_prep(const float* __restrict__ W_ih,
                                             const float* __restrict__ W_hh,
                                             const float* __restrict__ c2r,
                                             const float* __restrict__ h0f,
                                             const float* __restrict__ emb,
                                             const int* __restrict__ y_train,
                                             ushort_t* __restrict__ Wih,
                                             ushort_t* __restrict__ Whh,
                                             ushort_t* __restrict__ c2rT,
                                             ushort_t* __restrict__ Hh,
                                             ushort_t* __restrict__ Ebf) {
  const int r = blockIdx.x, l = threadIdx.x;
  if (r < 2048) {
    const int j = (r & 3) * 512 + (r >> 2);
    const float* s = W_ih + (size_t)j * 1536 + l * 8;
    *(uint4*)(Wih + (size_t)r * 512 + l * 8) = pack8(*(const float4*)s, *(const float4*)(s + 4));
  } else if (r < 4096) {
    const int rr = r - 2048;
    const int j = (rr & 3) * 512 + (rr >> 2);
    const float* s = W_hh + (size_t)j * 512 + l * 8;
    *(uint4*)(Whh + (size_t)rr * 512 + l * 8) = pack8(*(const float4*)s, *(const float4*)(s + 4));
  } else if (r < 4608) {
    const int n = r - 4096;
    float4 a, b;
    a.x = c2r[(size_t)(l * 8 + 0) * 512 + n]; a.y = c2r[(size_t)(l * 8 + 1) * 512 + n];
    a.z = c2r[(size_t)(l * 8 + 2) * 512 + n]; a.w = c2r[(size_t)(l * 8 + 3) * 512 + n];
    b.x = c2r[(size_t)(l * 8 + 4) * 512 + n]; b.y = c2r[(size_t)(l * 8 + 5) * 512 + n];
    b.z = c2r[(size_t)(l * 8 + 6) * 512 + n]; b.w = c2r[(size_t)(l * 8 + 7) * 512 + n];
    *(uint4*)(c2rT + (size_t)n * 512 + l * 8) = pack8(a, b);
  } else if (r < 4640) {
    // initial h state -> Hh[0] as [32 b][512 d]
    const int b = r - 4608;
    const float* s = h0f + b * 512 + l * 8;
    *(uint4*)(Hh + (size_t)b * 512 + l * 8) = pack8(*(const float4*)s, *(const float4*)(s + 4));
  } else {
    const int m = r - 4640;           // m' = t*32 + b
    const int t = m >> 5, b = m & 31;
    const int y = y_train[b * 64 + t];
    const float* s = emb + (size_t)y * 512 + l * 8;
    *(uint4*)(Ebf + (size_t)m * 512 + l * 8) = pack8(*(const float4*)s, *(const float4*)(s + 4));
  }
}

// ---------- readout_w transpose -> bf16 [32000][512] ----------
__global__ __launch_bounds__(256) void k_rt(const float* __restrict__ R, ushort_t* __restrict__ RT) {
  const int k0 = (blockIdx.x & 7) * 64;
  const int n0 = (blockIdx.x >> 3) * 64;
  __shared__ ushort_t tile[64][72];
  const int tid = threadIdx.x;
  const int kr = tid >> 2, c = tid & 3;
  for (int i = 0; i < 4; ++i) {
    float4 v = *(const float4*)(R + (size_t)(k0 + kr) * 32000 + n0 + (c * 4 + i) * 4);
    const int nn = (c * 4 + i) * 4;
    tile[nn + 0][kr] = f2bf(v.x);
    tile[nn + 1][kr] = f2bf(v.y);
    tile[nn + 2][kr] = f2bf(v.z);
    tile[nn + 3][kr] = f2bf(v.w);
  }
  __syncthreads();
  const int nr = tid >> 2, cc = tid & 3;
  for (int i = 0; i < 2; ++i) {
    uint4 v = *(const uint4*)(&tile[nr][cc * 16 + i * 8]);
    *(uint4*)(RT + (size_t)(n0 + nr) * 512 + k0 + cc * 16 + i * 8) = v;
  }
}

// ---------- shared GEMM: C[M][N] = A[M][512] * Bt[N][512]^T ----------
// Grid: blockIdx.x = M-tile, blockIdx.y = N-tile (x fastest -> m-tiles of one
// n-tile co-run, sharing the B-tile; A stays L2-resident).
// EPI 0: C f32 (ldc).  EPI 1: Cp bf16 = tanh(acc + ctx_read[b][col]), N=512.
// EPI 2: Cp bf16 gate layout [t][d][b][g] (row=t*32+b, col=4d+g).
template <int EPI, int SWZ>
__global__ __launch_bounds__(256) void k_gemm(const ushort_t* __restrict__ A,
                                              const ushort_t* __restrict__ Bt,
                                              float* __restrict__ C,
                                              ushort_t* __restrict__ Cp,
                                              const float* __restrict__ ctx_read,
                                              int ldc) {
  __shared__ ushort_t As[128 * 64];
  __shared__ ushort_t Bs[128 * 64];
  const int tid = threadIdx.x;
  const int l = tid & 63, wv = tid >> 6;
  const int wm = wv >> 1, wn = wv & 1;
  int bx = blockIdx.x, by = blockIdx.y;
  if (SWZ) {
    const int gx = gridDim.x;
    const int nwg = gx * gridDim.y;
    int flat = by * gx + bx;
    const int q = nwg >> 3;
    int nf = (flat & 7) * q + (flat >> 3);   // nwg % 8 == 0 -> bijective
    bx = nf % gx; by = nf / gx;
  }
  const int m0 = bx * 128, n0 = by * 128;
  const int lrow = l >> 3, lk = (l & 7) * 8;
  f32x4 acc[4][4] = {};

  for (int kt = 0; kt < 8; ++kt) {
    const int kbase = kt * 64;
#pragma unroll
    for (int i = 0; i < 4; ++i) {
      const int issue = wv * 4 + i;
      const int row = issue * 8 + lrow;
      gload_lds16(A + (size_t)(m0 + row) * 512 + kbase + lk, As + issue * 512);
      gload_lds16(Bt + (size_t)(n0 + row) * 512 + kbase + lk, Bs + issue * 512);
    }
    __syncthreads();
#pragma unroll
    for (int half = 0; half < 2; ++half) {
      const int kb = half * 32 + (l >> 4) * 8;
      bf16x8 af[4], bfr[4];
#pragma unroll
      for (int mi = 0; mi < 4; ++mi)
        af[mi] = *(const bf16x8*)(As + (wm * 64 + mi * 16 + (l & 15)) * 64 + kb);
#pragma unroll
      for (int ni = 0; ni < 4; ++ni)
        bfr[ni] = *(const bf16x8*)(Bs + (wn * 64 + ni * 16 + (l & 15)) * 64 + kb);
#pragma unroll
      for (int mi = 0; mi < 4; ++mi)
#pragma unroll
        for (int ni = 0; ni < 4; ++ni)
          acc[mi][ni] = __builtin_amdgcn_mfma_f32_16x16x32_bf16(af[mi], bfr[ni], acc[mi][ni], 0, 0, 0);
    }
    __syncthreads();
  }

#pragma unroll
  for (int mi = 0; mi < 4; ++mi) {
    const int row = m0 + wm * 64 + mi * 16 + (l >> 4) * 4;
#pragma unroll
    for (int ni = 0; ni < 4; ++ni) {
      const int col = n0 + wn * 64 + ni * 16 + (l & 15);
      if (EPI == 0) {
#pragma unroll
        for (int r = 0; r < 4; ++r)
          C[(size_t)(row + r) * (size_t)ldc + col] = acc[mi][ni][r];
      } else if (EPI == 1) {
        const int b = row >> 6;  // m = b*64+t
        const float cr = ctx_read[b * 512 + col];
#pragma unroll
        for (int r = 0; r < 4; ++r)
          Cp[(size_t)(row + r) * 512 + col] = f2bf(tanh_f(acc[mi][ni][r] + cr));
      } else {
        const int d = col >> 2, g = col & 3;
#pragma unroll
        for (int r = 0; r < 4; ++r) {
          const int rr = row + r;                   // m' = t*32 + b
          const int t = rr >> 5, b = rr & 31;
          Cp[((size_t)(t * 512 + d) * 32 + b) * 4 + g] = f2bf(acc[mi][ni][r]);
        }
      }
    }
  }
}

// ---------- persistent LSTM recurrence: 16 WGs x 4 waves (R6 skeleton) ----------
//  - h published via 16B sc0+sc1 write-through stores (LLC-visible);
//  - h staged via global_load_lds with sc1 aux (bypasses stale L1/L2, reads LLC);
//  - Hh is write-once per address (65-entry history) -> no WAR, no fences;
//  - flag store relaxed agent atomic, poll by tid<16;
//  - H_all HBM store issued AFTER the flag (overlaps the poll, off critical path).
__global__ __launch_bounds__(256, 1) void k_recur(const ushort_t* __restrict__ Eg2,
                                                  const float* __restrict__ F1,
                                                  const float* __restrict__ F0,
                                                  const ushort_t* __restrict__ Whh,
                                                  const float* __restrict__ c_init,
                                                  ushort_t* __restrict__ Hh,
                                                  ushort_t* __restrict__ H_all,
                                                  int* __restrict__ flags) {
  const int w = blockIdx.x;
  const int tid = threadIdx.x;
  const int l = tid & 63, v = tid >> 6;
  const int mh = v >> 1, nh = v & 1;
  const int q = l >> 4, ln = l & 15;
  __shared__ ushort_t hL[32 * 512];   // 32 KB staged h (XOR-swizzled)
  __shared__ ushort_t hOutL[32 * 40]; // 2.5 KB out bounce

  // W_hh' A-frags in registers: 64 frags
  bf16x8 WA[4][16];
#pragma unroll
  for (int mt = 0; mt < 4; ++mt)
#pragma unroll
    for (int kt = 0; kt < 16; ++kt)
      WA[mt][kt] = *(const bf16x8*)(Whh + (size_t)(128 * w + 64 * mh + mt * 16 + ln) * 512 + kt * 32 + q * 8);

  const int b = 16 * nh + ln;
  const int d0 = 32 * w + 16 * mh;   // + mt*4 + q
  float cst[4];
  float4 fv1[4], fv0[4];
  uint2 egc[4];
#pragma unroll
  for (int mt = 0; mt < 4; ++mt) {
    const int d = d0 + mt * 4 + q;
    cst[mt] = c_init[b * 512 + d];
    fv1[mt] = *(const float4*)(F1 + (d * 32 + b) * 4);
    fv0[mt] = *(const float4*)(F0 + (d * 32 + b) * 4);
    egc[mt] = *(const uint2*)(Eg2 + ((size_t)d * 32 + b) * 4);
  }

  bool bail = false;
  for (int t = 0; t < 64; ++t) {
    // stage h_{t-1} = Hh[t]: linear LDS dest, inverse-swizzled source, sc1 loads
    const char* hsrc = (const char*)Hh + (size_t)t * 32768;
#pragma unroll
    for (int rr = 0; rr < 8; ++rr) {
      const int R = v * 8 + rr;
      gload_lds16_sc(hsrc + R * 1024 + ((16 * l) ^ ((R & 7) << 4)), (char*)hL + R * 1024);
    }
    // prefetch NEXT step's gates (independent; overlaps the stage wait)
    uint2 egn[4];
    const int tn = (t + 1) & 63;
#pragma unroll
    for (int mt = 0; mt < 4; ++mt)
      egn[mt] = *(const uint2*)(Eg2 + ((size_t)(tn * 512 + d0 + mt * 4 + q) * 32 + b) * 4);
    __syncthreads();

    f32x4 acc[4] = {};
#pragma unroll
    for (int kt = 0; kt < 16; ++kt) {
      const int byteoff = (b * 1024 + kt * 64 + q * 16) ^ ((b & 7) << 4);
      bf16x8 hv = *(const bf16x8*)((const char*)hL + byteoff);
#pragma unroll
      for (int mt = 0; mt < 4; ++mt)
        acc[mt] = __builtin_amdgcn_mfma_f32_16x16x32_bf16(WA[mt][kt], hv, acc[mt], 0, 0, 0);
    }

    // pointwise: lane holds all 4 gates of (b, d)
#pragma unroll
    for (int mt = 0; mt < 4; ++mt) {
      const float4 fv = (t == 0) ? fv0[mt] : fv1[mt];
      float gi = acc[mt][0] + bfu2f(egc[mt].x & 0xFFFFu) + fv.x;
      float gf = acc[mt][1] + bfu2f(egc[mt].x >> 16) + fv.y;
      float gg = acc[mt][2] + bfu2f(egc[mt].y & 0xFFFFu) + fv.z;
      float go = acc[mt][3] + bfu2f(egc[mt].y >> 16) + fv.w;
      float c = sigm(gf) * cst[mt] + sigm(gi) * tanh_f(gg);
      cst[mt] = c;
      hOutL[b * 40 + 16 * mh + mt * 4 + q] = f2bf(sigm(go) * tanh_f(c));
      egc[mt] = egn[mt];
    }
    __syncthreads();                       // hOutL complete

    // publish h slice: 128 x 16B write-through (sc0 sc1) stores -> LLC
    u32x4 val;
    int b2 = 0, c16 = 0;
    if (tid < 128) {
      b2 = tid >> 2; c16 = (tid & 3) * 8;
      val = *(const u32x4*)(hOutL + b2 * 40 + c16);
      ushort_t* hp = Hh + (size_t)(t + 1) * 16384 + b2 * 512 + 32 * w + c16;
      asm volatile("global_store_dwordx4 %0, %1, off sc0 sc1" :: "v"(hp), "v"(val) : "memory");
    }
    __syncthreads();                       // publish drained (vmcnt0 before barrier)

    if (t < 63 && tid == 0)
      __hip_atomic_store(flags + w * 32, t + 1, __ATOMIC_RELAXED, __HIP_MEMORY_SCOPE_AGENT);
    // H_all store AFTER the flag: its HBM latency overlaps the poll below.
    if (tid < 128)
      __builtin_nontemporal_store(val, (u32x4*)(H_all + (size_t)(b2 * 64 + t) * 512 + 32 * w + c16));

    if (t < 63) {
      if (!bail && tid < 16) {
        int spins = 0;
        while (__hip_atomic_load(flags + tid * 32, __ATOMIC_RELAXED, __HIP_MEMORY_SCOPE_AGENT) < t + 1) {
          __builtin_amdgcn_s_sleep(1);
          if (++spins > 2000000) { bail = true; break; }
        }
      }
      __syncthreads();                     // also drains the H_all store + lds reads
    }
  }
}

// ---------- launcher ----------
extern "C" void kernel_launch(void* const* d_in, const int* in_sizes, int n_in,
                              void* d_out, int out_size, void* d_ws, size_t ws_size,
                              hipStream_t stream) {
  const float* x_enc   = (const float*)d_in[0];
  const float* x_enc_k = (const float*)d_in[1];
  const float* h0f     = (const float*)d_in[2];
  const float* c0f     = (const float*)d_in[3];
  const int*   y_train = (const int*)d_in[5];
  const float* emb     = (const float*)d_in[7];
  const float* W_ih    = (const float*)d_in[8];
  const float* W_hh    = (const float*)d_in[9];
  const float* b_ih    = (const float*)d_in[10];
  const float* b_hh    = (const float*)d_in[11];
  const float* w_att   = (const float*)d_in[14];
  const float* c2r     = (const float*)d_in[16];
  const float* Rw      = (const float*)d_in[17];
  float* out = (float*)d_out;
  char* ws = (char*)d_ws;

  int*      flags    = (int*)(ws + WS_FLAGS);
  float*    ctx      = (float*)(ws + WS_CTX);
  float*    ctxT     = (float*)(ws + WS_CTXT);
  float*    ctx_read = (float*)(ws + WS_CTXRD);
  float*    F1r      = (float*)(ws + WS_F1);
  float*    F0r      = (float*)(ws + WS_F0);
  ushort_t* Ebf      = (ushort_t*)(ws + WS_EBF);
  ushort_t* Wih      = (ushort_t*)(ws + WS_WIH);
  ushort_t* Whh      = (ushort_t*)(ws + WS_WHH);
  ushort_t* c2rT     = (ushort_t*)(ws + WS_C2RT);
  ushort_t* RT       = (ushort_t*)(ws + WS_RT);
  ushort_t* Eg2      = (ushort_t*)(ws + WS_EG);
  ushort_t* Hh       = (ushort_t*)(ws + WS_HH);
  ushort_t* H        = (ushort_t*)(ws + WS_H);
  ushort_t* P        = (ushort_t*)(ws + WS_P);

  (void)hipMemsetAsync(flags, 0, 16384, stream);
  k_ctx<<<32, 256, 0, stream>>>(x_enc_k, x_enc, w_att, ctx, ctxT);
  k_feed<<<320, 256, 0, stream>>>(ctxT, W_ih, b_ih, b_hh, c2r, F1r, F0r, ctx_read);
  k_prep<<<6688, 64, 0, stream>>>(W_ih, W_hh, c2r, h0f, emb, y_train, Wih, Whh, c2rT, Hh, Ebf);
  k_rt<<<4000, 256, 0, stream>>>(Rw, RT);
  k_gemm<2, 0><<<dim3(16, 16), 256, 0, stream>>>(Ebf, Wih, nullptr, Eg2, nullptr, 0);
  k_recur<<<16, 256, 0, stream>>>(Eg2, F1r, F0r, Whh, c0f, Hh, H, flags);
  k_gemm<1, 0><<<dim3(16, 4), 256, 0, stream>>>(H, c2rT, nullptr, P, ctx_read, 512);
  k_gemm<0, 1><<<dim3(16, 250), 256, 0, stream>>>(P, RT, out, nullptr, nullptr, 32000);
  (void)in_sizes; (void)n_in; (void)out_size; (void)ws_size;
}

// Round 9
// 591.817 us; speedup vs baseline: 1.0439x; 1.0439x over previous
//
#include <hip/hip_runtime.h>

typedef unsigned short ushort_t;
typedef __bf16 bf16x8 __attribute__((ext_vector_type(8)));
typedef float f32x4 __attribute__((ext_vector_type(4)));
typedef unsigned u32x4 __attribute__((ext_vector_type(4)));

// ---------- workspace layout (bytes) ----------
#define WS_FLAGS   0x0        // 16 flags, 128B apart
#define WS_CTX     0x14000    // ctx [32][1024] f32
#define WS_CTXT    0x34000    // ctx_T [1024][32] f32
#define WS_CTXRD   0x54000    // ctx_read [32][512] f32
#define WS_F1      0x64000    // F1r [512][32][4] f32 (feed+bias)
#define WS_F0      0xA4000    // F0r (bias only)
#define WS_EBF     0xE4000    // E_bf16 [2048][512]   (m' = t*32+b)
#define WS_WIH     0x2E4000   // Wih' bf16 [2048][512] (j' = 4d+g order)
#define WS_WHH     0x4E4000   // Whh' bf16 [2048][512]
#define WS_C2RT    0x6E4000   // c2r_top^T bf16 [512][512]
#define WS_RT      0x764000   // readout^T bf16 [32000][512]
#define WS_EG      0x26A4000  // Eg2 bf16 [64 t][512 d][32 b][4 g]  (8 MB)
#define WS_HH      0x2EA4000  // Hh bf16 [65 ts][32 b][512 d] write-once history (2.08 MB)
#define WS_H       0x36A4000  // H bf16 [2048][512]  (m = b*64+t)
#define WS_P       0x38A4000  // P bf16 [2048][512]

__device__ __forceinline__ unsigned short f2bf(float f) {
  unsigned u = __builtin_bit_cast(unsigned, f);
  u = (u + 0x7FFFu + ((u >> 16) & 1u)) >> 16;
  return (unsigned short)u;
}
__device__ __forceinline__ float bfu2f(unsigned s) {
  return __builtin_bit_cast(float, s << 16);
}
__device__ __forceinline__ uint4 pack8(float4 a, float4 b) {
  uint4 o;
  o.x = (unsigned)f2bf(a.x) | ((unsigned)f2bf(a.y) << 16);
  o.y = (unsigned)f2bf(a.z) | ((unsigned)f2bf(a.w) << 16);
  o.z = (unsigned)f2bf(b.x) | ((unsigned)f2bf(b.y) << 16);
  o.w = (unsigned)f2bf(b.z) | ((unsigned)f2bf(b.w) << 16);
  return o;
}
__device__ __forceinline__ float sigm(float x) { return 1.0f / (1.0f + __expf(-x)); }
__device__ __forceinline__ float tanh_f(float x) {
  float a = fabsf(x);
  float t = __expf(-2.0f * a);
  float r = (1.0f - t) / (1.0f + t);
  return x < 0.0f ? -r : r;
}
__device__ __forceinline__ void gload_lds16(const void* g, void* l) {
  __builtin_amdgcn_global_load_lds((const __attribute__((address_space(1))) unsigned*)g,
                                   (__attribute__((address_space(3))) unsigned*)l, 16, 0, 0);
}
// sc1 = agent-coherent load: bypasses (misses) this XCD's L1/L2, reads LLC.
__device__ __forceinline__ void gload_lds16_sc(const void* g, void* l) {
  __builtin_amdgcn_global_load_lds((const __attribute__((address_space(1))) unsigned*)g,
                                   (__attribute__((address_space(3))) unsigned*)l, 16, 0, 16);
}

// ---------- Phase A: attention weights + ctx (step-independent) ----------
__global__ __launch_bounds__(256) void k_ctx(const float* __restrict__ xk,
                                             const float* __restrict__ xenc,
                                             const float* __restrict__ watt,
                                             float* __restrict__ ctx,
                                             float* __restrict__ ctxT) {
  const int b = blockIdx.x, tid = threadIdx.x;
  __shared__ float part[256];
  __shared__ float attw[64];
  const int lq = tid >> 2, q = tid & 3;
  const float* row = xk + ((size_t)b * 64 + lq) * 512 + q * 128;
  const float* wa = watt + q * 128;
  float s = 0.0f;
  for (int i = 0; i < 128; i += 4) {
    float4 a = *(const float4*)(row + i);
    float4 w = *(const float4*)(wa + i);
    s += a.x * w.x + a.y * w.y + a.z * w.z + a.w * w.w;
  }
  part[tid] = s;
  __syncthreads();
  if (tid < 64) {
    float sc = part[tid * 4] + part[tid * 4 + 1] + part[tid * 4 + 2] + part[tid * 4 + 3];
    float m = sc;
    for (int off = 32; off; off >>= 1) m = fmaxf(m, __shfl_xor(m, off));
    float e = __expf(sc - m);
    float ssum = e;
    for (int off = 32; off; off >>= 1) ssum += __shfl_xor(ssum, off);
    attw[tid] = e / ssum;
  }
  __syncthreads();
  for (int v = tid; v < 1024; v += 256) {
    float a = 0.0f;
    for (int L = 0; L < 64; ++L) a += attw[L] * xenc[((size_t)b * 64 + L) * 1024 + v];
    ctx[b * 1024 + v] = a;
    ctxT[v * 32 + b] = a;
  }
}

// ---------- Phase B: feed term + ctx_read ----------
__global__ __launch_bounds__(256) void k_feed(const float* __restrict__ ctxT,
                                              const float* __restrict__ W_ih,
                                              const float* __restrict__ bih,
                                              const float* __restrict__ bhh,
                                              const float* __restrict__ c2r,
                                              float* __restrict__ F1r,
                                              float* __restrict__ F0r,
                                              float* __restrict__ ctx_read) {
  const int wg = blockIdx.x, tid = threadIdx.x;
  const int b = tid & 31, sub = tid >> 5;
  if (wg < 256) {
    const int jp = wg * 8 + sub;          // j' row
    const int d = jp >> 2, g = jp & 3;
    const int j = g * 512 + d;            // original gate row
    const float* wr = W_ih + (size_t)j * 1536 + 512;
    float s = 0.0f;
    for (int v = 0; v < 1024; v += 4) {
      float4 wv = *(const float4*)(wr + v);
      s += ctxT[(v + 0) * 32 + b] * wv.x + ctxT[(v + 1) * 32 + b] * wv.y +
           ctxT[(v + 2) * 32 + b] * wv.z + ctxT[(v + 3) * 32 + b] * wv.w;
    }
    float bias = bih[j] + bhh[j];
    F1r[((d * 32) + b) * 4 + g] = s + bias;
    F0r[((d * 32) + b) * 4 + g] = bias;
  } else {
    const int n = (wg - 256) * 8 + sub;
    const float* cr = c2r + (size_t)512 * 512;  // ctx rows of ctx2read_w
    float s = 0.0f;
    for (int v = 0; v < 1024; ++v) s += ctxT[v * 32 + b] * cr[(size_t)v * 512 + n];
    ctx_read[b * 512 + n] = s;
  }
}

// ---------- Phase C: converts / gathers (c2rT moved into k_recur extras) ----------
__global__ __launch_bounds__(64) void k_prep(const float* __restrict__ W_ih,
                                             const float* __restrict__ W_hh,
                                             const float* __restrict__ h0f,
                                             const float* __restrict__ emb,
                                             const int* __restrict__ y_train,
                                             ushort_t* __restrict__ Wih,
                                             ushort_t* __restrict__ Whh,
                                             ushort_t* __restrict__ Hh,
                                             ushort_t* __restrict__ Ebf) {
  const int r = blockIdx.x, l = threadIdx.x;
  if (r < 2048) {
    const int j = (r & 3) * 512 + (r >> 2);
    const float* s = W_ih + (size_t)j * 1536 + l * 8;
    *(uint4*)(Wih + (size_t)r * 512 + l * 8) = pack8(*(const float4*)s, *(const float4*)(s + 4));
  } else if (r < 4096) {
    const int rr = r - 2048;
    const int j = (rr & 3) * 512 + (rr >> 2);
    const float* s = W_hh + (size_t)j * 512 + l * 8;
    *(uint4*)(Whh + (size_t)rr * 512 + l * 8) = pack8(*(const float4*)s, *(const float4*)(s + 4));
  } else if (r < 4128) {
    // initial h state -> Hh[0] as [32 b][512 d]
    const int b = r - 4096;
    const float* s = h0f + b * 512 + l * 8;
    *(uint4*)(Hh + (size_t)b * 512 + l * 8) = pack8(*(const float4*)s, *(const float4*)(s + 4));
  } else {
    const int m = r - 4128;           // m' = t*32 + b
    const int t = m >> 5, b = m & 31;
    const int y = y_train[b * 64 + t];
    const float* s = emb + (size_t)y * 512 + l * 8;
    *(uint4*)(Ebf + (size_t)m * 512 + l * 8) = pack8(*(const float4*)s, *(const float4*)(s + 4));
  }
}

// ---------- shared GEMM: C[M][N] = A[M][512] * Bt[N][512]^T ----------
// Grid: blockIdx.x = M-tile, blockIdx.y = N-tile (x fastest -> m-tiles of one
// n-tile co-run, sharing the B-tile; A stays L2-resident).
// EPI 0: C f32 (ldc).  EPI 1: Cp bf16 = tanh(acc + ctx_read[b][col]), N=512.
// EPI 2: Cp bf16 gate layout [t][d][b][g] (row=t*32+b, col=4d+g).
template <int EPI, int SWZ>
__global__ __launch_bounds__(256) void k_gemm(const ushort_t* __restrict__ A,
                                              const ushort_t* __restrict__ Bt,
                                              float* __restrict__ C,
                                              ushort_t* __restrict__ Cp,
                                              const float* __restrict__ ctx_read,
                                              int ldc) {
  __shared__ ushort_t As[128 * 64];
  __shared__ ushort_t Bs[128 * 64];
  const int tid = threadIdx.x;
  const int l = tid & 63, wv = tid >> 6;
  const int wm = wv >> 1, wn = wv & 1;
  int bx = blockIdx.x, by = blockIdx.y;
  if (SWZ) {
    const int gx = gridDim.x;
    const int nwg = gx * gridDim.y;
    int flat = by * gx + bx;
    const int q = nwg >> 3;
    int nf = (flat & 7) * q + (flat >> 3);   // nwg % 8 == 0 -> bijective
    bx = nf % gx; by = nf / gx;
  }
  const int m0 = bx * 128, n0 = by * 128;
  const int lrow = l >> 3, lk = (l & 7) * 8;
  f32x4 acc[4][4] = {};

  for (int kt = 0; kt < 8; ++kt) {
    const int kbase = kt * 64;
#pragma unroll
    for (int i = 0; i < 4; ++i) {
      const int issue = wv * 4 + i;
      const int row = issue * 8 + lrow;
      gload_lds16(A + (size_t)(m0 + row) * 512 + kbase + lk, As + issue * 512);
      gload_lds16(Bt + (size_t)(n0 + row) * 512 + kbase + lk, Bs + issue * 512);
    }
    __syncthreads();
#pragma unroll
    for (int half = 0; half < 2; ++half) {
      const int kb = half * 32 + (l >> 4) * 8;
      bf16x8 af[4], bfr[4];
#pragma unroll
      for (int mi = 0; mi < 4; ++mi)
        af[mi] = *(const bf16x8*)(As + (wm * 64 + mi * 16 + (l & 15)) * 64 + kb);
#pragma unroll
      for (int ni = 0; ni < 4; ++ni)
        bfr[ni] = *(const bf16x8*)(Bs + (wn * 64 + ni * 16 + (l & 15)) * 64 + kb);
#pragma unroll
      for (int mi = 0; mi < 4; ++mi)
#pragma unroll
        for (int ni = 0; ni < 4; ++ni)
          acc[mi][ni] = __builtin_amdgcn_mfma_f32_16x16x32_bf16(af[mi], bfr[ni], acc[mi][ni], 0, 0, 0);
    }
    __syncthreads();
  }

#pragma unroll
  for (int mi = 0; mi < 4; ++mi) {
    const int row = m0 + wm * 64 + mi * 16 + (l >> 4) * 4;
#pragma unroll
    for (int ni = 0; ni < 4; ++ni) {
      const int col = n0 + wn * 64 + ni * 16 + (l & 15);
      if (EPI == 0) {
#pragma unroll
        for (int r = 0; r < 4; ++r)
          C[(size_t)(row + r) * (size_t)ldc + col] = acc[mi][ni][r];
      } else if (EPI == 1) {
        const int b = row >> 6;  // m = b*64+t
        const float cr = ctx_read[b * 512 + col];
#pragma unroll
        for (int r = 0; r < 4; ++r)
          Cp[(size_t)(row + r) * 512 + col] = f2bf(tanh_f(acc[mi][ni][r] + cr));
      } else {
        const int d = col >> 2, g = col & 3;
#pragma unroll
        for (int r = 0; r < 4; ++r) {
          const int rr = row + r;                   // m' = t*32 + b
          const int t = rr >> 5, b = rr & 31;
          Cp[((size_t)(t * 512 + d) * 32 + b) * 4 + g] = f2bf(acc[mi][ni][r]);
        }
      }
    }
  }
}

// ---------- persistent LSTM recurrence + folded independent prep work ----------
// blockIdx 0..15   : R8's proven 16-WG recurrence (byte-identical worker path).
// blockIdx 16..4015: readout_w transpose tile (was k_rt) -- consumed only by the
//                    logits GEMM, which launches after this kernel completes.
// blockIdx 4016..4143: c2r_top^T convert (was k_prep branch) -- consumed by gemm<1>.
// Extras never touch flags and terminate unconditionally -> no deadlock surface;
// they run on the ~240 CUs that sit idle during the recurrence.
__global__ __launch_bounds__(256, 1) void k_recur(const ushort_t* __restrict__ Eg2,
                                                  const float* __restrict__ F1,
                                                  const float* __restrict__ F0,
                                                  const ushort_t* __restrict__ Whh,
                                                  const float* __restrict__ c_init,
                                                  ushort_t* __restrict__ Hh,
                                                  ushort_t* __restrict__ H_all,
                                                  int* __restrict__ flags,
                                                  const float* __restrict__ Rw,
                                                  ushort_t* __restrict__ RT,
                                                  const float* __restrict__ c2r,
                                                  ushort_t* __restrict__ c2rT) {
  const int bid = blockIdx.x;
  const int tid = threadIdx.x;
  __shared__ __align__(16) char smem[35328];   // workers: hL(32K)+hOutL(2.5K); extras: tile(9.2K)

  if (bid >= 16) {
    if (bid < 4016) {
      // ---- readout_w transpose tile (identical math to old k_rt) ----
      ushort_t (*tile)[72] = (ushort_t(*)[72])smem;
      const int id = bid - 16;
      const int k0 = (id & 7) * 64;
      const int n0 = (id >> 3) * 64;
      const int kr = tid >> 2, c = tid & 3;
      for (int i = 0; i < 4; ++i) {
        float4 vv = *(const float4*)(Rw + (size_t)(k0 + kr) * 32000 + n0 + (c * 4 + i) * 4);
        const int nn = (c * 4 + i) * 4;
        tile[nn + 0][kr] = f2bf(vv.x);
        tile[nn + 1][kr] = f2bf(vv.y);
        tile[nn + 2][kr] = f2bf(vv.z);
        tile[nn + 3][kr] = f2bf(vv.w);
      }
      __syncthreads();
      const int nr = tid >> 2, cc = tid & 3;
      for (int i = 0; i < 2; ++i) {
        uint4 vv = *(const uint4*)(&tile[nr][cc * 16 + i * 8]);
        *(uint4*)(RT + (size_t)(n0 + nr) * 512 + k0 + cc * 16 + i * 8) = vv;
      }
    } else {
      // ---- c2r_top^T convert: 128 WGs x 256 thr cover [512 n][512 k] ----
      const int n = (bid - 4016) * 4 + (tid >> 6);
      const int l = tid & 63;
      float4 a, b;
      a.x = c2r[(size_t)(l * 8 + 0) * 512 + n]; a.y = c2r[(size_t)(l * 8 + 1) * 512 + n];
      a.z = c2r[(size_t)(l * 8 + 2) * 512 + n]; a.w = c2r[(size_t)(l * 8 + 3) * 512 + n];
      b.x = c2r[(size_t)(l * 8 + 4) * 512 + n]; b.y = c2r[(size_t)(l * 8 + 5) * 512 + n];
      b.z = c2r[(size_t)(l * 8 + 6) * 512 + n]; b.w = c2r[(size_t)(l * 8 + 7) * 512 + n];
      *(uint4*)(c2rT + (size_t)n * 512 + l * 8) = pack8(a, b);
    }
    return;
  }

  // ---------------- worker path (byte-identical to R8) ----------------
  const int w = bid;
  const int l = tid & 63, v = tid >> 6;
  const int mh = v >> 1, nh = v & 1;
  const int q = l >> 4, ln = l & 15;
  ushort_t* hL = (ushort_t*)smem;              // 32 KB staged h (XOR-swizzled)
  ushort_t* hOutL = (ushort_t*)(smem + 32768); // 2.5 KB out bounce (stride 40)

  bf16x8 WA[4][16];
#pragma unroll
  for (int mt = 0; mt < 4; ++mt)
#pragma unroll
    for (int kt = 0; kt < 16; ++kt)
      WA[mt][kt] = *(const bf16x8*)(Whh + (size_t)(128 * w + 64 * mh + mt * 16 + ln) * 512 + kt * 32 + q * 8);

  const int b = 16 * nh + ln;
  const int d0 = 32 * w + 16 * mh;   // + mt*4 + q
  float cst[4];
  float4 fv1[4], fv0[4];
  uint2 egc[4];
#pragma unroll
  for (int mt = 0; mt < 4; ++mt) {
    const int d = d0 + mt * 4 + q;
    cst[mt] = c_init[b * 512 + d];
    fv1[mt] = *(const float4*)(F1 + (d * 32 + b) * 4);
    fv0[mt] = *(const float4*)(F0 + (d * 32 + b) * 4);
    egc[mt] = *(const uint2*)(Eg2 + ((size_t)d * 32 + b) * 4);
  }

  bool bail = false;
  for (int t = 0; t < 64; ++t) {
    // stage h_{t-1} = Hh[t]: linear LDS dest, inverse-swizzled source, sc1 loads
    const char* hsrc = (const char*)Hh + (size_t)t * 32768;
#pragma unroll
    for (int rr = 0; rr < 8; ++rr) {
      const int R = v * 8 + rr;
      gload_lds16_sc(hsrc + R * 1024 + ((16 * l) ^ ((R & 7) << 4)), (char*)hL + R * 1024);
    }
    // prefetch NEXT step's gates (independent; overlaps the stage wait)
    uint2 egn[4];
    const int tn = (t + 1) & 63;
#pragma unroll
    for (int mt = 0; mt < 4; ++mt)
      egn[mt] = *(const uint2*)(Eg2 + ((size_t)(tn * 512 + d0 + mt * 4 + q) * 32 + b) * 4);
    __syncthreads();

    f32x4 acc[4] = {};
#pragma unroll
    for (int kt = 0; kt < 16; ++kt) {
      const int byteoff = (b * 1024 + kt * 64 + q * 16) ^ ((b & 7) << 4);
      bf16x8 hv = *(const bf16x8*)((const char*)hL + byteoff);
#pragma unroll
      for (int mt = 0; mt < 4; ++mt)
        acc[mt] = __builtin_amdgcn_mfma_f32_16x16x32_bf16(WA[mt][kt], hv, acc[mt], 0, 0, 0);
    }

    // pointwise: lane holds all 4 gates of (b, d)
#pragma unroll
    for (int mt = 0; mt < 4; ++mt) {
      const float4 fv = (t == 0) ? fv0[mt] : fv1[mt];
      float gi = acc[mt][0] + bfu2f(egc[mt].x & 0xFFFFu) + fv.x;
      float gf = acc[mt][1] + bfu2f(egc[mt].x >> 16) + fv.y;
      float gg = acc[mt][2] + bfu2f(egc[mt].y & 0xFFFFu) + fv.z;
      float go = acc[mt][3] + bfu2f(egc[mt].y >> 16) + fv.w;
      float c = sigm(gf) * cst[mt] + sigm(gi) * tanh_f(gg);
      cst[mt] = c;
      hOutL[b * 40 + 16 * mh + mt * 4 + q] = f2bf(sigm(go) * tanh_f(c));
      egc[mt] = egn[mt];
    }
    __syncthreads();                       // hOutL complete

    // publish h slice: 128 x 16B write-through (sc0 sc1) stores -> LLC
    u32x4 val;
    int b2 = 0, c16 = 0;
    if (tid < 128) {
      b2 = tid >> 2; c16 = (tid & 3) * 8;
      val = *(const u32x4*)(hOutL + b2 * 40 + c16);
      ushort_t* hp = Hh + (size_t)(t + 1) * 16384 + b2 * 512 + 32 * w + c16;
      asm volatile("global_store_dwordx4 %0, %1, off sc0 sc1" :: "v"(hp), "v"(val) : "memory");
    }
    __syncthreads();                       // publish drained (vmcnt0 before barrier)

    if (t < 63 && tid == 0)
      __hip_atomic_store(flags + w * 32, t + 1, __ATOMIC_RELAXED, __HIP_MEMORY_SCOPE_AGENT);
    // H_all store AFTER the flag: its HBM latency overlaps the poll below.
    if (tid < 128)
      __builtin_nontemporal_store(val, (u32x4*)(H_all + (size_t)(b2 * 64 + t) * 512 + 32 * w + c16));

    if (t < 63) {
      if (!bail && tid < 16) {
        int spins = 0;
        while (__hip_atomic_load(flags + tid * 32, __ATOMIC_RELAXED, __HIP_MEMORY_SCOPE_AGENT) < t + 1) {
          __builtin_amdgcn_s_sleep(1);
          if (++spins > 2000000) { bail = true; break; }
        }
      }
      __syncthreads();                     // also drains the H_all store + lds reads
    }
  }
}

// ---------- launcher ----------
extern "C" void kernel_launch(void* const* d_in, const int* in_sizes, int n_in,
                              void* d_out, int out_size, void* d_ws, size_t ws_size,
                              hipStream_t stream) {
  const float* x_enc   = (const float*)d_in[0];
  const float* x_enc_k = (const float*)d_in[1];
  const float* h0f     = (const float*)d_in[2];
  const float* c0f     = (const float*)d_in[3];
  const int*   y_train = (const int*)d_in[5];
  const float* emb     = (const float*)d_in[7];
  const float* W_ih    = (const float*)d_in[8];
  const float* W_hh    = (const float*)d_in[9];
  const float* b_ih    = (const float*)d_in[10];
  const float* b_hh    = (const float*)d_in[11];
  const float* w_att   = (const float*)d_in[14];
  const float* c2r     = (const float*)d_in[16];
  const float* Rw      = (const float*)d_in[17];
  float* out = (float*)d_out;
  char* ws = (char*)d_ws;

  int*      flags    = (int*)(ws + WS_FLAGS);
  float*    ctx      = (float*)(ws + WS_CTX);
  float*    ctxT     = (float*)(ws + WS_CTXT);
  float*    ctx_read = (float*)(ws + WS_CTXRD);
  float*    F1r      = (float*)(ws + WS_F1);
  float*    F0r      = (float*)(ws + WS_F0);
  ushort_t* Ebf      = (ushort_t*)(ws + WS_EBF);
  ushort_t* Wih      = (ushort_t*)(ws + WS_WIH);
  ushort_t* Whh      = (ushort_t*)(ws + WS_WHH);
  ushort_t* c2rT     = (ushort_t*)(ws + WS_C2RT);
  ushort_t* RT       = (ushort_t*)(ws + WS_RT);
  ushort_t* Eg2      = (ushort_t*)(ws + WS_EG);
  ushort_t* Hh       = (ushort_t*)(ws + WS_HH);
  ushort_t* H        = (ushort_t*)(ws + WS_H);
  ushort_t* P        = (ushort_t*)(ws + WS_P);

  (void)hipMemsetAsync(flags, 0, 16384, stream);
  k_ctx<<<32, 256, 0, stream>>>(x_enc_k, x_enc, w_att, ctx, ctxT);
  k_feed<<<320, 256, 0, stream>>>(ctxT, W_ih, b_ih, b_hh, c2r, F1r, F0r, ctx_read);
  k_prep<<<6176, 64, 0, stream>>>(W_ih, W_hh, h0f, emb, y_train, Wih, Whh, Hh, Ebf);
  k_gemm<2, 0><<<dim3(16, 16), 256, 0, stream>>>(Ebf, Wih, nullptr, Eg2, nullptr, 0);
  k_recur<<<4144, 256, 0, stream>>>(Eg2, F1r, F0r, Whh, c0f, Hh, H, flags, Rw, RT, c2r, c2rT);
  k_gemm<1, 0><<<dim3(16, 4), 256, 0, stream>>>(H, c2rT, nullptr, P, ctx_read, 512);
  k_gemm<0, 1><<<dim3(16, 250), 256, 0, stream>>>(P, RT, out, nullptr, nullptr, 32000);
  (void)in_sizes; (void)n_in; (void)out_size; (void)ws_size;
}

// Round 10
// 466.573 us; speedup vs baseline: 1.3241x; 1.2684x over previous
//
#include <hip/hip_runtime.h>

typedef unsigned short ushort_t;
typedef __bf16 bf16x8 __attribute__((ext_vector_type(8)));
typedef float f32x4 __attribute__((ext_vector_type(4)));
typedef unsigned u32x4 __attribute__((ext_vector_type(4)));

// ---------- workspace layout (bytes) ----------
#define WS_FLAGS   0x0        // worker flags [16]x128B; P-flags at +2048
#define WS_CTX     0x14000    // ctx [32][1024] f32
#define WS_CTXT    0x34000    // ctx_T [1024][32] f32
#define WS_CTXRD   0x54000    // ctx_read [32][512] f32
#define WS_F1      0x64000    // F1r [512][32][4] f32 (feed+bias)
#define WS_F0      0xA4000    // F0r (bias only)
#define WS_EBF     0xE4000    // E_bf16 [2048][512]   (m' = t*32+b)
#define WS_WIH     0x2E4000   // Wih' bf16 [2048][512] (j' = 4d+g order)
#define WS_WHH     0x4E4000   // Whh' bf16 [2048][512]
#define WS_EG      0x26A4000  // Eg2 bf16 [64 t][512 d][32 b][4 g]  (8 MB)
#define WS_HH      0x2EA4000  // Hh bf16 [65 ts][32 b][512 d] write-once history
#define WS_P       0x38A4000  // P bf16 [64 t][32 b][512 n] write-once (2 MB)

__device__ __forceinline__ unsigned short f2bf(float f) {
  unsigned u = __builtin_bit_cast(unsigned, f);
  u = (u + 0x7FFFu + ((u >> 16) & 1u)) >> 16;
  return (unsigned short)u;
}
__device__ __forceinline__ float bfu2f(unsigned s) {
  return __builtin_bit_cast(float, s << 16);
}
__device__ __forceinline__ uint4 pack8(float4 a, float4 b) {
  uint4 o;
  o.x = (unsigned)f2bf(a.x) | ((unsigned)f2bf(a.y) << 16);
  o.y = (unsigned)f2bf(a.z) | ((unsigned)f2bf(a.w) << 16);
  o.z = (unsigned)f2bf(b.x) | ((unsigned)f2bf(b.y) << 16);
  o.w = (unsigned)f2bf(b.z) | ((unsigned)f2bf(b.w) << 16);
  return o;
}
__device__ __forceinline__ float sigm(float x) { return 1.0f / (1.0f + __expf(-x)); }
__device__ __forceinline__ float tanh_f(float x) {
  float a = fabsf(x);
  float t = __expf(-2.0f * a);
  float r = (1.0f - t) / (1.0f + t);
  return x < 0.0f ? -r : r;
}
__device__ __forceinline__ void gload_lds16(const void* g, void* l) {
  __builtin_amdgcn_global_load_lds((const __attribute__((address_space(1))) unsigned*)g,
                                   (__attribute__((address_space(3))) unsigned*)l, 16, 0, 0);
}
// sc1 = agent-coherent load: bypasses this XCD's (possibly stale) L1/L2, reads LLC.
__device__ __forceinline__ void gload_lds16_sc(const void* g, void* l) {
  __builtin_amdgcn_global_load_lds((const __attribute__((address_space(1))) unsigned*)g,
                                   (__attribute__((address_space(3))) unsigned*)l, 16, 0, 16);
}

// ---------- Phase A: attention weights + ctx (step-independent) ----------
__global__ __launch_bounds__(256) void k_ctx(const float* __restrict__ xk,
                                             const float* __restrict__ xenc,
                                             const float* __restrict__ watt,
                                             float* __restrict__ ctx,
                                             float* __restrict__ ctxT) {
  const int b = blockIdx.x, tid = threadIdx.x;
  __shared__ float part[256];
  __shared__ float attw[64];
  const int lq = tid >> 2, q = tid & 3;
  const float* row = xk + ((size_t)b * 64 + lq) * 512 + q * 128;
  const float* wa = watt + q * 128;
  float s = 0.0f;
  for (int i = 0; i < 128; i += 4) {
    float4 a = *(const float4*)(row + i);
    float4 w = *(const float4*)(wa + i);
    s += a.x * w.x + a.y * w.y + a.z * w.z + a.w * w.w;
  }
  part[tid] = s;
  __syncthreads();
  if (tid < 64) {
    float sc = part[tid * 4] + part[tid * 4 + 1] + part[tid * 4 + 2] + part[tid * 4 + 3];
    float m = sc;
    for (int off = 32; off; off >>= 1) m = fmaxf(m, __shfl_xor(m, off));
    float e = __expf(sc - m);
    float ssum = e;
    for (int off = 32; off; off >>= 1) ssum += __shfl_xor(ssum, off);
    attw[tid] = e / ssum;
  }
  __syncthreads();
  for (int v = tid; v < 1024; v += 256) {
    float a = 0.0f;
    for (int L = 0; L < 64; ++L) a += attw[L] * xenc[((size_t)b * 64 + L) * 1024 + v];
    ctx[b * 1024 + v] = a;
    ctxT[v * 32 + b] = a;
  }
}

// ---------- Phase B: feed term + ctx_read ----------
__global__ __launch_bounds__(256) void k_feed(const float* __restrict__ ctxT,
                                              const float* __restrict__ W_ih,
                                              const float* __restrict__ bih,
                                              const float* __restrict__ bhh,
                                              const float* __restrict__ c2r,
                                              float* __restrict__ F1r,
                                              float* __restrict__ F0r,
                                              float* __restrict__ ctx_read) {
  const int wg = blockIdx.x, tid = threadIdx.x;
  const int b = tid & 31, sub = tid >> 5;
  if (wg < 256) {
    const int jp = wg * 8 + sub;          // j' row
    const int d = jp >> 2, g = jp & 3;
    const int j = g * 512 + d;            // original gate row
    const float* wr = W_ih + (size_t)j * 1536 + 512;
    float s = 0.0f;
    for (int v = 0; v < 1024; v += 4) {
      float4 wv = *(const float4*)(wr + v);
      s += ctxT[(v + 0) * 32 + b] * wv.x + ctxT[(v + 1) * 32 + b] * wv.y +
           ctxT[(v + 2) * 32 + b] * wv.z + ctxT[(v + 3) * 32 + b] * wv.w;
    }
    float bias = bih[j] + bhh[j];
    F1r[((d * 32) + b) * 4 + g] = s + bias;
    F0r[((d * 32) + b) * 4 + g] = bias;
  } else {
    const int n = (wg - 256) * 8 + sub;
    const float* cr = c2r + (size_t)512 * 512;  // ctx rows of ctx2read_w
    float s = 0.0f;
    for (int v = 0; v < 1024; ++v) s += ctxT[v * 32 + b] * cr[(size_t)v * 512 + n];
    ctx_read[b * 512 + n] = s;
  }
}

// ---------- Phase C: converts / gathers ----------
__global__ __launch_bounds__(64) void k_prep(const float* __restrict__ W_ih,
                                             const float* __restrict__ W_hh,
                                             const float* __restrict__ h0f,
                                             const float* __restrict__ emb,
                                             const int* __restrict__ y_train,
                                             ushort_t* __restrict__ Wih,
                                             ushort_t* __restrict__ Whh,
                                             ushort_t* __restrict__ Hh,
                                             ushort_t* __restrict__ Ebf) {
  const int r = blockIdx.x, l = threadIdx.x;
  if (r < 2048) {
    const int j = (r & 3) * 512 + (r >> 2);
    const float* s = W_ih + (size_t)j * 1536 + l * 8;
    *(uint4*)(Wih + (size_t)r * 512 + l * 8) = pack8(*(const float4*)s, *(const float4*)(s + 4));
  } else if (r < 4096) {
    const int rr = r - 2048;
    const int j = (rr & 3) * 512 + (rr >> 2);
    const float* s = W_hh + (size_t)j * 512 + l * 8;
    *(uint4*)(Whh + (size_t)rr * 512 + l * 8) = pack8(*(const float4*)s, *(const float4*)(s + 4));
  } else if (r < 4128) {
    // initial h state -> Hh[0] as [32 b][512 d]
    const int b = r - 4096;
    const float* s = h0f + b * 512 + l * 8;
    *(uint4*)(Hh + (size_t)b * 512 + l * 8) = pack8(*(const float4*)s, *(const float4*)(s + 4));
  } else {
    const int m = r - 4128;           // m' = t*32 + b
    const int t = m >> 5, b = m & 31;
    const int y = y_train[b * 64 + t];
    const float* s = emb + (size_t)y * 512 + l * 8;
    *(uint4*)(Ebf + (size_t)m * 512 + l * 8) = pack8(*(const float4*)s, *(const float4*)(s + 4));
  }
}

// ---------- GEMM for Eg: C[M][N] = A[M][512] * Bt[N][512]^T, gate layout out ----------
template <int EPI>
__global__ __launch_bounds__(256) void k_gemm(const ushort_t* __restrict__ A,
                                              const ushort_t* __restrict__ Bt,
                                              ushort_t* __restrict__ Cp) {
  __shared__ ushort_t As[128 * 64];
  __shared__ ushort_t Bs[128 * 64];
  const int tid = threadIdx.x;
  const int l = tid & 63, wv = tid >> 6;
  const int wm = wv >> 1, wn = wv & 1;
  const int m0 = blockIdx.x * 128, n0 = blockIdx.y * 128;
  const int lrow = l >> 3, lk = (l & 7) * 8;
  f32x4 acc[4][4] = {};

  for (int kt = 0; kt < 8; ++kt) {
    const int kbase = kt * 64;
#pragma unroll
    for (int i = 0; i < 4; ++i) {
      const int issue = wv * 4 + i;
      const int row = issue * 8 + lrow;
      gload_lds16(A + (size_t)(m0 + row) * 512 + kbase + lk, As + issue * 512);
      gload_lds16(Bt + (size_t)(n0 + row) * 512 + kbase + lk, Bs + issue * 512);
    }
    __syncthreads();
#pragma unroll
    for (int half = 0; half < 2; ++half) {
      const int kb = half * 32 + (l >> 4) * 8;
      bf16x8 af[4], bfr[4];
#pragma unroll
      for (int mi = 0; mi < 4; ++mi)
        af[mi] = *(const bf16x8*)(As + (wm * 64 + mi * 16 + (l & 15)) * 64 + kb);
#pragma unroll
      for (int ni = 0; ni < 4; ++ni)
        bfr[ni] = *(const bf16x8*)(Bs + (wn * 64 + ni * 16 + (l & 15)) * 64 + kb);
#pragma unroll
      for (int mi = 0; mi < 4; ++mi)
#pragma unroll
        for (int ni = 0; ni < 4; ++ni)
          acc[mi][ni] = __builtin_amdgcn_mfma_f32_16x16x32_bf16(af[mi], bfr[ni], acc[mi][ni], 0, 0, 0);
    }
    __syncthreads();
  }

#pragma unroll
  for (int mi = 0; mi < 4; ++mi) {
    const int row = m0 + wm * 64 + mi * 16 + (l >> 4) * 4;
#pragma unroll
    for (int ni = 0; ni < 4; ++ni) {
      const int col = n0 + wn * 64 + ni * 16 + (l & 15);
      const int d = col >> 2, g = col & 3;
#pragma unroll
      for (int r = 0; r < 4; ++r) {
        const int rr = row + r;                   // m' = t*32 + b
        const int t = rr >> 5, b = rr & 31;
        Cp[((size_t)(t * 512 + d) * 32 + b) * 4 + g] = f2bf(acc[mi][ni][r]);
      }
    }
  }
}

// ---------- recurrence + pipelined tail (P + logits), 149 co-resident blocks ----------
// bid 0..15  : workers (R9-proven path; flag set EVERY step, final value 64)
// bid 16..23 : P-producers: block c owns P cols [64c,64c+64); per t: poll worker flags
//              >= t+1, sc-stage Hh[t+1], P[t]-slice = tanh(Hh[t+1] @ c2r_top + cr),
//              publish linear sc0sc1, P-flag[c] = t+1.
// bid 24..148: logits: block e owns out cols [256e,256e+256); B = bf16(Rw cols) in regs;
//              per t: poll 8 P-flags >= t+1, sc-stage P[t] (swizzled), 128 MFMA, write out.
// All 149 blocks co-resident by capacity -> flags are monotonic state, no deadlock;
// every spin has a bail (fail-visible, never hangs).
__global__ __launch_bounds__(256, 1) void k_recur(const ushort_t* __restrict__ Eg2,
                                                  const float* __restrict__ F1,
                                                  const float* __restrict__ F0,
                                                  const ushort_t* __restrict__ Whh,
                                                  const float* __restrict__ c_init,
                                                  ushort_t* __restrict__ Hh,
                                                  ushort_t* __restrict__ P,
                                                  int* __restrict__ flags,
                                                  const float* __restrict__ c2r,
                                                  const float* __restrict__ ctx_read,
                                                  const float* __restrict__ Rw,
                                                  float* __restrict__ out) {
  const int bid = blockIdx.x;
  const int tid = threadIdx.x;
  __shared__ __align__(16) char smem[37376];   // 32K stage + bounce (32x40 / 32x72)

  const int l = tid & 63, v = tid >> 6;
  const int q = l >> 4, ln = l & 15;

  if (bid >= 24) {
    // ---------------- logits path ----------------
    const int e = bid - 24;
    const int n0 = 256 * e;
    ushort_t* aL = (ushort_t*)smem;
    bf16x8 B[4][16];
#pragma unroll
    for (int nf = 0; nf < 4; ++nf)
#pragma unroll
      for (int kf = 0; kf < 16; ++kf) {
        bf16x8 tmp;
#pragma unroll
        for (int j = 0; j < 8; ++j)
          tmp[j] = (__bf16)Rw[(size_t)(kf * 32 + q * 8 + j) * 32000 + n0 + 64 * v + nf * 16 + ln];
        B[nf][kf] = tmp;
      }
    bool bail = false;
    for (int t = 0; t < 64; ++t) {
      if (!bail && tid < 8) {
        int spins = 0;
        while (__hip_atomic_load(flags + 512 + tid * 32, __ATOMIC_RELAXED, __HIP_MEMORY_SCOPE_AGENT) < t + 1) {
          __builtin_amdgcn_s_sleep(1);
          if (++spins > 2000000) { bail = true; break; }
        }
      }
      __syncthreads();
      const char* psrc = (const char*)P + (size_t)t * 32768;
#pragma unroll
      for (int rr = 0; rr < 8; ++rr) {
        const int R = v * 8 + rr;
        gload_lds16_sc(psrc + R * 1024 + ((16 * l) ^ ((R & 7) << 4)), (char*)aL + R * 1024);
      }
      __syncthreads();
      f32x4 acc[2][4] = {};
#pragma unroll
      for (int kf = 0; kf < 16; ++kf)
#pragma unroll
        for (int mf = 0; mf < 2; ++mf) {
          const int row = mf * 16 + ln;
          const int byteoff = (row * 1024 + kf * 64 + q * 16) ^ ((row & 7) << 4);
          bf16x8 a = *(const bf16x8*)((const char*)aL + byteoff);
#pragma unroll
          for (int nf = 0; nf < 4; ++nf)
            acc[mf][nf] = __builtin_amdgcn_mfma_f32_16x16x32_bf16(a, B[nf][kf], acc[mf][nf], 0, 0, 0);
        }
#pragma unroll
      for (int mf = 0; mf < 2; ++mf)
#pragma unroll
        for (int nf = 0; nf < 4; ++nf)
#pragma unroll
          for (int r = 0; r < 4; ++r) {
            const int brow = mf * 16 + q * 4 + r;
            out[(size_t)(brow * 64 + t) * 32000 + n0 + 64 * v + nf * 16 + ln] = acc[mf][nf][r];
          }
    }
    return;
  }

  if (bid >= 16) {
    // ---------------- P-producer path ----------------
    const int c = bid - 16;
    ushort_t* aL = (ushort_t*)smem;
    ushort_t* pOut = (ushort_t*)(smem + 32768);  // [32][72]
    const int myCol = 64 * c + 16 * v + ln;
    bf16x8 B[16];
#pragma unroll
    for (int kf = 0; kf < 16; ++kf) {
      bf16x8 tmp;
#pragma unroll
      for (int j = 0; j < 8; ++j)
        tmp[j] = (__bf16)c2r[(size_t)(kf * 32 + q * 8 + j) * 512 + myCol];
      B[kf] = tmp;
    }
    float crv[2][4];
#pragma unroll
    for (int mf = 0; mf < 2; ++mf)
#pragma unroll
      for (int r = 0; r < 4; ++r)
        crv[mf][r] = ctx_read[(mf * 16 + q * 4 + r) * 512 + myCol];
    bool bail = false;
    for (int t = 0; t < 64; ++t) {
      if (!bail && tid < 16) {
        int spins = 0;
        while (__hip_atomic_load(flags + tid * 32, __ATOMIC_RELAXED, __HIP_MEMORY_SCOPE_AGENT) < t + 1) {
          __builtin_amdgcn_s_sleep(1);
          if (++spins > 2000000) { bail = true; break; }
        }
      }
      __syncthreads();
      const char* hsrc = (const char*)Hh + (size_t)(t + 1) * 32768;
#pragma unroll
      for (int rr = 0; rr < 8; ++rr) {
        const int R = v * 8 + rr;
        gload_lds16_sc(hsrc + R * 1024 + ((16 * l) ^ ((R & 7) << 4)), (char*)aL + R * 1024);
      }
      __syncthreads();
      f32x4 acc[2] = {};
#pragma unroll
      for (int kf = 0; kf < 16; ++kf)
#pragma unroll
        for (int mf = 0; mf < 2; ++mf) {
          const int row = mf * 16 + ln;
          const int byteoff = (row * 1024 + kf * 64 + q * 16) ^ ((row & 7) << 4);
          bf16x8 a = *(const bf16x8*)((const char*)aL + byteoff);
          acc[mf] = __builtin_amdgcn_mfma_f32_16x16x32_bf16(a, B[kf], acc[mf], 0, 0, 0);
        }
#pragma unroll
      for (int mf = 0; mf < 2; ++mf)
#pragma unroll
        for (int r = 0; r < 4; ++r)
          pOut[(mf * 16 + q * 4 + r) * 72 + 16 * v + ln] = f2bf(tanh_f(acc[mf][r] + crv[mf][r]));
      __syncthreads();
      {
        const int b = tid >> 3, ch = tid & 7;
        u32x4 pv = *(const u32x4*)(pOut + b * 72 + ch * 8);
        char* pp = (char*)P + (size_t)t * 32768 + b * 1024 + 128 * c + ch * 16;
        asm volatile("global_store_dwordx4 %0, %1, off sc0 sc1" :: "v"(pp), "v"(pv) : "memory");
      }
      __syncthreads();   // publish drained (vmcnt0 before barrier)
      if (tid == 0)
        __hip_atomic_store(flags + 512 + c * 32, t + 1, __ATOMIC_RELAXED, __HIP_MEMORY_SCOPE_AGENT);
    }
    return;
  }

  // ---------------- worker path (R9-proven) ----------------
  const int w = bid;
  const int mh = v >> 1, nh = v & 1;
  ushort_t* hL = (ushort_t*)smem;
  ushort_t* hOutL = (ushort_t*)(smem + 32768);  // [32][40]

  bf16x8 WA[4][16];
#pragma unroll
  for (int mt = 0; mt < 4; ++mt)
#pragma unroll
    for (int kt = 0; kt < 16; ++kt)
      WA[mt][kt] = *(const bf16x8*)(Whh + (size_t)(128 * w + 64 * mh + mt * 16 + ln) * 512 + kt * 32 + q * 8);

  const int b = 16 * nh + ln;
  const int d0 = 32 * w + 16 * mh;
  float cst[4];
  float4 fv1[4], fv0[4];
  uint2 egc[4];
#pragma unroll
  for (int mt = 0; mt < 4; ++mt) {
    const int d = d0 + mt * 4 + q;
    cst[mt] = c_init[b * 512 + d];
    fv1[mt] = *(const float4*)(F1 + (d * 32 + b) * 4);
    fv0[mt] = *(const float4*)(F0 + (d * 32 + b) * 4);
    egc[mt] = *(const uint2*)(Eg2 + ((size_t)d * 32 + b) * 4);
  }

  bool bail = false;
  for (int t = 0; t < 64; ++t) {
    const char* hsrc = (const char*)Hh + (size_t)t * 32768;
#pragma unroll
    for (int rr = 0; rr < 8; ++rr) {
      const int R = v * 8 + rr;
      gload_lds16_sc(hsrc + R * 1024 + ((16 * l) ^ ((R & 7) << 4)), (char*)hL + R * 1024);
    }
    uint2 egn[4];
    const int tn = (t + 1) & 63;
#pragma unroll
    for (int mt = 0; mt < 4; ++mt)
      egn[mt] = *(const uint2*)(Eg2 + ((size_t)(tn * 512 + d0 + mt * 4 + q) * 32 + b) * 4);
    __syncthreads();

    f32x4 acc[4] = {};
#pragma unroll
    for (int kt = 0; kt < 16; ++kt) {
      const int byteoff = (b * 1024 + kt * 64 + q * 16) ^ ((b & 7) << 4);
      bf16x8 hv = *(const bf16x8*)((const char*)hL + byteoff);
#pragma unroll
      for (int mt = 0; mt < 4; ++mt)
        acc[mt] = __builtin_amdgcn_mfma_f32_16x16x32_bf16(WA[mt][kt], hv, acc[mt], 0, 0, 0);
    }

#pragma unroll
    for (int mt = 0; mt < 4; ++mt) {
      const float4 fv = (t == 0) ? fv0[mt] : fv1[mt];
      float gi = acc[mt][0] + bfu2f(egc[mt].x & 0xFFFFu) + fv.x;
      float gf = acc[mt][1] + bfu2f(egc[mt].x >> 16) + fv.y;
      float gg = acc[mt][2] + bfu2f(egc[mt].y & 0xFFFFu) + fv.z;
      float go = acc[mt][3] + bfu2f(egc[mt].y >> 16) + fv.w;
      float c = sigm(gf) * cst[mt] + sigm(gi) * tanh_f(gg);
      cst[mt] = c;
      hOutL[b * 40 + 16 * mh + mt * 4 + q] = f2bf(sigm(go) * tanh_f(c));
      egc[mt] = egn[mt];
    }
    __syncthreads();

    if (tid < 128) {
      const int b2 = tid >> 2, c16 = (tid & 3) * 8;
      const u32x4 val = *(const u32x4*)(hOutL + b2 * 40 + c16);
      ushort_t* hp = Hh + (size_t)(t + 1) * 16384 + b2 * 512 + 32 * w + c16;
      asm volatile("global_store_dwordx4 %0, %1, off sc0 sc1" :: "v"(hp), "v"(val) : "memory");
    }
    __syncthreads();                       // publish drained (vmcnt0 before barrier)

    if (tid == 0)
      __hip_atomic_store(flags + w * 32, t + 1, __ATOMIC_RELAXED, __HIP_MEMORY_SCOPE_AGENT);

    if (t < 63) {
      if (!bail && tid < 16) {
        int spins = 0;
        while (__hip_atomic_load(flags + tid * 32, __ATOMIC_RELAXED, __HIP_MEMORY_SCOPE_AGENT) < t + 1) {
          __builtin_amdgcn_s_sleep(1);
          if (++spins > 2000000) { bail = true; break; }
        }
      }
      __syncthreads();
    }
  }
}

// ---------- launcher ----------
extern "C" void kernel_launch(void* const* d_in, const int* in_sizes, int n_in,
                              void* d_out, int out_size, void* d_ws, size_t ws_size,
                              hipStream_t stream) {
  const float* x_enc   = (const float*)d_in[0];
  const float* x_enc_k = (const float*)d_in[1];
  const float* h0f     = (const float*)d_in[2];
  const float* c0f     = (const float*)d_in[3];
  const int*   y_train = (const int*)d_in[5];
  const float* emb     = (const float*)d_in[7];
  const float* W_ih    = (const float*)d_in[8];
  const float* W_hh    = (const float*)d_in[9];
  const float* b_ih    = (const float*)d_in[10];
  const float* b_hh    = (const float*)d_in[11];
  const float* w_att   = (const float*)d_in[14];
  const float* c2r     = (const float*)d_in[16];
  const float* Rw      = (const float*)d_in[17];
  float* out = (float*)d_out;
  char* ws = (char*)d_ws;

  int*      flags    = (int*)(ws + WS_FLAGS);
  float*    ctx      = (float*)(ws + WS_CTX);
  float*    ctxT     = (float*)(ws + WS_CTXT);
  float*    ctx_read = (float*)(ws + WS_CTXRD);
  float*    F1r      = (float*)(ws + WS_F1);
  float*    F0r      = (float*)(ws + WS_F0);
  ushort_t* Ebf      = (ushort_t*)(ws + WS_EBF);
  ushort_t* Wih      = (ushort_t*)(ws + WS_WIH);
  ushort_t* Whh      = (ushort_t*)(ws + WS_WHH);
  ushort_t* Eg2      = (ushort_t*)(ws + WS_EG);
  ushort_t* Hh       = (ushort_t*)(ws + WS_HH);
  ushort_t* P        = (ushort_t*)(ws + WS_P);

  (void)hipMemsetAsync(flags, 0, 16384, stream);
  k_ctx<<<32, 256, 0, stream>>>(x_enc_k, x_enc, w_att, ctx, ctxT);
  k_feed<<<320, 256, 0, stream>>>(ctxT, W_ih, b_ih, b_hh, c2r, F1r, F0r, ctx_read);
  k_prep<<<6176, 64, 0, stream>>>(W_ih, W_hh, h0f, emb, y_train, Wih, Whh, Hh, Ebf);
  k_gemm<2><<<dim3(16, 16), 256, 0, stream>>>(Ebf, Wih, Eg2);
  k_recur<<<149, 256, 0, stream>>>(Eg2, F1r, F0r, Whh, c0f, Hh, P, flags, c2r, ctx_read, Rw, out);
  (void)in_sizes; (void)n_in; (void)out_size; (void)ws_size;
}

// Round 11
// 449.801 us; speedup vs baseline: 1.3735x; 1.0373x over previous
//
#include <hip/hip_runtime.h>

typedef unsigned short ushort_t;
typedef __bf16 bf16x8 __attribute__((ext_vector_type(8)));
typedef float f32x4 __attribute__((ext_vector_type(4)));
typedef unsigned u32x4 __attribute__((ext_vector_type(4)));

// ---------- workspace layout (bytes) ----------
#define WS_FLAGS   0x0        // worker flags [16]x128B; P-flags at +2048; 4KB zeroed by k_pre1
#define WS_CTX     0x14000    // ctx [32][1024] f32
#define WS_CTXT    0x34000    // ctx_T [1024][32] f32
#define WS_CTXRD   0x54000    // ctx_read [32][512] f32
#define WS_F1      0x64000    // F1r [512][32][4] f32 (feed+bias)
#define WS_F0      0xA4000    // F0r (bias only)
#define WS_EBF     0xE4000    // E_bf16 [2048][512]   (m' = t*32+b)
#define WS_WIH     0x2E4000   // Wih' bf16 [2048][512] (j' = 4d+g order)
#define WS_WHH     0x4E4000   // Whh' bf16 [2048][512]
#define WS_EG      0x26A4000  // Eg2 bf16 [64 t][512 d][32 b][4 g]  (8 MB)
#define WS_HH      0x2EA4000  // Hh bf16 [65 ts][32 b][512 d] write-once history
#define WS_P       0x38A4000  // P bf16 [64 t][32 b][512 n] write-once (2 MB)

__device__ __forceinline__ unsigned short f2bf(float f) {
  unsigned u = __builtin_bit_cast(unsigned, f);
  u = (u + 0x7FFFu + ((u >> 16) & 1u)) >> 16;
  return (unsigned short)u;
}
__device__ __forceinline__ float bfu2f(unsigned s) {
  return __builtin_bit_cast(float, s << 16);
}
__device__ __forceinline__ uint4 pack8(float4 a, float4 b) {
  uint4 o;
  o.x = (unsigned)f2bf(a.x) | ((unsigned)f2bf(a.y) << 16);
  o.y = (unsigned)f2bf(a.z) | ((unsigned)f2bf(a.w) << 16);
  o.z = (unsigned)f2bf(b.x) | ((unsigned)f2bf(b.y) << 16);
  o.w = (unsigned)f2bf(b.z) | ((unsigned)f2bf(b.w) << 16);
  return o;
}
__device__ __forceinline__ float sigm(float x) { return 1.0f / (1.0f + __expf(-x)); }
__device__ __forceinline__ float tanh_f(float x) {
  float a = fabsf(x);
  float t = __expf(-2.0f * a);
  float r = (1.0f - t) / (1.0f + t);
  return x < 0.0f ? -r : r;
}
__device__ __forceinline__ void gload_lds16(const void* g, void* l) {
  __builtin_amdgcn_global_load_lds((const __attribute__((address_space(1))) unsigned*)g,
                                   (__attribute__((address_space(3))) unsigned*)l, 16, 0, 0);
}
// sc1 = agent-coherent load: bypasses this XCD's (possibly stale) L1/L2, reads LLC.
__device__ __forceinline__ void gload_lds16_sc(const void* g, void* l) {
  __builtin_amdgcn_global_load_lds((const __attribute__((address_space(1))) unsigned*)g,
                                   (__attribute__((address_space(3))) unsigned*)l, 16, 0, 16);
}

// ---------- k_pre1: ctx/softmax (bid<32) + converts/gathers (bid 32..1575) + flag zero ----------
__global__ __launch_bounds__(256) void k_pre1(const float* __restrict__ xk,
                                              const float* __restrict__ xenc,
                                              const float* __restrict__ watt,
                                              float* __restrict__ ctx,
                                              float* __restrict__ ctxT,
                                              const float* __restrict__ W_ih,
                                              const float* __restrict__ W_hh,
                                              const float* __restrict__ h0f,
                                              const float* __restrict__ emb,
                                              const int* __restrict__ y_train,
                                              ushort_t* __restrict__ Wih,
                                              ushort_t* __restrict__ Whh,
                                              ushort_t* __restrict__ Hh,
                                              ushort_t* __restrict__ Ebf,
                                              int* __restrict__ flags) {
  const int bid = blockIdx.x, tid = threadIdx.x;

  if (bid < 32) {
    // ---- attention weights + ctx (step-independent) ----
    const int b = bid;
    __shared__ float part[256];
    __shared__ float attw[64];
    const int lq = tid >> 2, q = tid & 3;
    const float* row = xk + ((size_t)b * 64 + lq) * 512 + q * 128;
    const float* wa = watt + q * 128;
    float s = 0.0f;
    for (int i = 0; i < 128; i += 4) {
      float4 a = *(const float4*)(row + i);
      float4 w = *(const float4*)(wa + i);
      s += a.x * w.x + a.y * w.y + a.z * w.z + a.w * w.w;
    }
    part[tid] = s;
    __syncthreads();
    if (tid < 64) {
      float sc = part[tid * 4] + part[tid * 4 + 1] + part[tid * 4 + 2] + part[tid * 4 + 3];
      float m = sc;
      for (int off = 32; off; off >>= 1) m = fmaxf(m, __shfl_xor(m, off));
      float e = __expf(sc - m);
      float ssum = e;
      for (int off = 32; off; off >>= 1) ssum += __shfl_xor(ssum, off);
      attw[tid] = e / ssum;
    }
    __syncthreads();
    for (int v = tid; v < 1024; v += 256) {
      float a = 0.0f;
      for (int L = 0; L < 64; ++L) a += attw[L] * xenc[((size_t)b * 64 + L) * 1024 + v];
      ctx[b * 1024 + v] = a;
      ctxT[v * 32 + b] = a;
    }
    return;
  }
  if (bid == 1576) {
    ((int*)flags)[tid] = 0;               // zero 1 KB... (4B x 256) x4 below
    ((int*)flags)[256 + tid] = 0;
    ((int*)flags)[512 + tid] = 0;
    ((int*)flags)[768 + tid] = 0;         // 4 KB total: worker flags + P flags
    return;
  }

  // ---- converts / gathers (old k_prep, 4 rows per 256-thread block) ----
  const int r = (bid - 32) * 4 + (tid >> 6);
  const int l = tid & 63;
  if (r < 2048) {
    const int j = (r & 3) * 512 + (r >> 2);
    const float* s = W_ih + (size_t)j * 1536 + l * 8;
    *(uint4*)(Wih + (size_t)r * 512 + l * 8) = pack8(*(const float4*)s, *(const float4*)(s + 4));
  } else if (r < 4096) {
    const int rr = r - 2048;
    const int j = (rr & 3) * 512 + (rr >> 2);
    const float* s = W_hh + (size_t)j * 512 + l * 8;
    *(uint4*)(Whh + (size_t)rr * 512 + l * 8) = pack8(*(const float4*)s, *(const float4*)(s + 4));
  } else if (r < 4128) {
    const int b = r - 4096;
    const float* s = h0f + b * 512 + l * 8;
    *(uint4*)(Hh + (size_t)b * 512 + l * 8) = pack8(*(const float4*)s, *(const float4*)(s + 4));
  } else {
    const int m = r - 4128;           // m' = t*32 + b
    const int t = m >> 5, b = m & 31;
    const int y = y_train[b * 64 + t];
    const float* s = emb + (size_t)y * 512 + l * 8;
    *(uint4*)(Ebf + (size_t)m * 512 + l * 8) = pack8(*(const float4*)s, *(const float4*)(s + 4));
  }
}

// ---------- k_pre2: feed GEMV (bid<320) + Eg GEMM (bid 320..575) ----------
__global__ __launch_bounds__(256) void k_pre2(const float* __restrict__ ctxT,
                                              const float* __restrict__ W_ih,
                                              const float* __restrict__ bih,
                                              const float* __restrict__ bhh,
                                              const float* __restrict__ c2r,
                                              float* __restrict__ F1r,
                                              float* __restrict__ F0r,
                                              float* __restrict__ ctx_read,
                                              const ushort_t* __restrict__ A,
                                              const ushort_t* __restrict__ Bt,
                                              ushort_t* __restrict__ Cp) {
  const int bid = blockIdx.x, tid = threadIdx.x;
  __shared__ __align__(16) char smem[32768];

  if (bid < 320) {
    // ---- feed term + ctx_read (old k_feed) ----
    const int wg = bid;
    const int b = tid & 31, sub = tid >> 5;
    if (wg < 256) {
      const int jp = wg * 8 + sub;          // j' row
      const int d = jp >> 2, g = jp & 3;
      const int j = g * 512 + d;            // original gate row
      const float* wr = W_ih + (size_t)j * 1536 + 512;
      float s = 0.0f;
      for (int v = 0; v < 1024; v += 4) {
        float4 wv = *(const float4*)(wr + v);
        s += ctxT[(v + 0) * 32 + b] * wv.x + ctxT[(v + 1) * 32 + b] * wv.y +
             ctxT[(v + 2) * 32 + b] * wv.z + ctxT[(v + 3) * 32 + b] * wv.w;
      }
      float bias = bih[j] + bhh[j];
      F1r[((d * 32) + b) * 4 + g] = s + bias;
      F0r[((d * 32) + b) * 4 + g] = bias;
    } else {
      const int n = (wg - 256) * 8 + sub;
      const float* cr = c2r + (size_t)512 * 512;  // ctx rows of ctx2read_w
      float s = 0.0f;
      for (int v = 0; v < 1024; ++v) s += ctxT[v * 32 + b] * cr[(size_t)v * 512 + n];
      ctx_read[b * 512 + n] = s;
    }
    return;
  }

  // ---- Eg GEMM (old k_gemm<2>): C = Ebf @ Wih^T -> gate layout [t][d][b][g] ----
  ushort_t* As = (ushort_t*)smem;
  ushort_t* Bs = (ushort_t*)(smem + 16384);
  const int gb = bid - 320;
  const int m0 = (gb & 15) * 128, n0 = (gb >> 4) * 128;
  const int l = tid & 63, wv = tid >> 6;
  const int wm = wv >> 1, wn = wv & 1;
  const int lrow = l >> 3, lk = (l & 7) * 8;
  f32x4 acc[4][4] = {};

  for (int kt = 0; kt < 8; ++kt) {
    const int kbase = kt * 64;
#pragma unroll
    for (int i = 0; i < 4; ++i) {
      const int issue = wv * 4 + i;
      const int row = issue * 8 + lrow;
      gload_lds16(A + (size_t)(m0 + row) * 512 + kbase + lk, As + issue * 512);
      gload_lds16(Bt + (size_t)(n0 + row) * 512 + kbase + lk, Bs + issue * 512);
    }
    __syncthreads();
#pragma unroll
    for (int half = 0; half < 2; ++half) {
      const int kb = half * 32 + (l >> 4) * 8;
      bf16x8 af[4], bfr[4];
#pragma unroll
      for (int mi = 0; mi < 4; ++mi)
        af[mi] = *(const bf16x8*)(As + (wm * 64 + mi * 16 + (l & 15)) * 64 + kb);
#pragma unroll
      for (int ni = 0; ni < 4; ++ni)
        bfr[ni] = *(const bf16x8*)(Bs + (wn * 64 + ni * 16 + (l & 15)) * 64 + kb);
#pragma unroll
      for (int mi = 0; mi < 4; ++mi)
#pragma unroll
        for (int ni = 0; ni < 4; ++ni)
          acc[mi][ni] = __builtin_amdgcn_mfma_f32_16x16x32_bf16(af[mi], bfr[ni], acc[mi][ni], 0, 0, 0);
    }
    __syncthreads();
  }

#pragma unroll
  for (int mi = 0; mi < 4; ++mi) {
    const int row = m0 + wm * 64 + mi * 16 + (l >> 4) * 4;
#pragma unroll
    for (int ni = 0; ni < 4; ++ni) {
      const int col = n0 + wn * 64 + ni * 16 + (l & 15);
      const int d = col >> 2, g = col & 3;
#pragma unroll
      for (int r = 0; r < 4; ++r) {
        const int rr = row + r;                   // m' = t*32 + b
        const int t = rr >> 5, b = rr & 31;
        Cp[((size_t)(t * 512 + d) * 32 + b) * 4 + g] = f2bf(acc[mi][ni][r]);
      }
    }
  }
}

// ---------- recurrence + pipelined tail (P + logits), 149 co-resident blocks ----------
// bid 0..15  : workers (proven path; flag set EVERY step, final value 64)
// bid 16..23 : P-producers; bid 24..148: logits consumers (see R10 notes).
__global__ __launch_bounds__(256, 1) void k_recur(const ushort_t* __restrict__ Eg2,
                                                  const float* __restrict__ F1,
                                                  const float* __restrict__ F0,
                                                  const ushort_t* __restrict__ Whh,
                                                  const float* __restrict__ c_init,
                                                  ushort_t* __restrict__ Hh,
                                                  ushort_t* __restrict__ P,
                                                  int* __restrict__ flags,
                                                  const float* __restrict__ c2r,
                                                  const float* __restrict__ ctx_read,
                                                  const float* __restrict__ Rw,
                                                  float* __restrict__ out) {
  const int bid = blockIdx.x;
  const int tid = threadIdx.x;
  __shared__ __align__(16) char smem[37376];   // 32K stage + bounce (32x40 / 32x72)

  const int l = tid & 63, v = tid >> 6;
  const int q = l >> 4, ln = l & 15;

  if (bid >= 24) {
    // ---------------- logits path ----------------
    const int e = bid - 24;
    const int n0 = 256 * e;
    ushort_t* aL = (ushort_t*)smem;
    bf16x8 B[4][16];
#pragma unroll
    for (int nf = 0; nf < 4; ++nf)
#pragma unroll
      for (int kf = 0; kf < 16; ++kf) {
        bf16x8 tmp;
#pragma unroll
        for (int j = 0; j < 8; ++j)
          tmp[j] = (__bf16)Rw[(size_t)(kf * 32 + q * 8 + j) * 32000 + n0 + 64 * v + nf * 16 + ln];
        B[nf][kf] = tmp;
      }
    bool bail = false;
    for (int t = 0; t < 64; ++t) {
      if (!bail && tid < 8) {
        int spins = 0;
        while (__hip_atomic_load(flags + 512 + tid * 32, __ATOMIC_RELAXED, __HIP_MEMORY_SCOPE_AGENT) < t + 1) {
          __builtin_amdgcn_s_sleep(1);
          if (++spins > 2000000) { bail = true; break; }
        }
      }
      __syncthreads();
      const char* psrc = (const char*)P + (size_t)t * 32768;
#pragma unroll
      for (int rr = 0; rr < 8; ++rr) {
        const int R = v * 8 + rr;
        gload_lds16_sc(psrc + R * 1024 + ((16 * l) ^ ((R & 7) << 4)), (char*)aL + R * 1024);
      }
      __syncthreads();
      f32x4 acc[2][4] = {};
#pragma unroll
      for (int kf = 0; kf < 16; ++kf)
#pragma unroll
        for (int mf = 0; mf < 2; ++mf) {
          const int row = mf * 16 + ln;
          const int byteoff = (row * 1024 + kf * 64 + q * 16) ^ ((row & 7) << 4);
          bf16x8 a = *(const bf16x8*)((const char*)aL + byteoff);
#pragma unroll
          for (int nf = 0; nf < 4; ++nf)
            acc[mf][nf] = __builtin_amdgcn_mfma_f32_16x16x32_bf16(a, B[nf][kf], acc[mf][nf], 0, 0, 0);
        }
#pragma unroll
      for (int mf = 0; mf < 2; ++mf)
#pragma unroll
        for (int nf = 0; nf < 4; ++nf)
#pragma unroll
          for (int r = 0; r < 4; ++r) {
            const int brow = mf * 16 + q * 4 + r;
            out[(size_t)(brow * 64 + t) * 32000 + n0 + 64 * v + nf * 16 + ln] = acc[mf][nf][r];
          }
    }
    return;
  }

  if (bid >= 16) {
    // ---------------- P-producer path ----------------
    const int c = bid - 16;
    ushort_t* aL = (ushort_t*)smem;
    ushort_t* pOut = (ushort_t*)(smem + 32768);  // [32][72]
    const int myCol = 64 * c + 16 * v + ln;
    bf16x8 B[16];
#pragma unroll
    for (int kf = 0; kf < 16; ++kf) {
      bf16x8 tmp;
#pragma unroll
      for (int j = 0; j < 8; ++j)
        tmp[j] = (__bf16)c2r[(size_t)(kf * 32 + q * 8 + j) * 512 + myCol];
      B[kf] = tmp;
    }
    float crv[2][4];
#pragma unroll
    for (int mf = 0; mf < 2; ++mf)
#pragma unroll
      for (int r = 0; r < 4; ++r)
        crv[mf][r] = ctx_read[(mf * 16 + q * 4 + r) * 512 + myCol];
    bool bail = false;
    for (int t = 0; t < 64; ++t) {
      if (!bail && tid < 16) {
        int spins = 0;
        while (__hip_atomic_load(flags + tid * 32, __ATOMIC_RELAXED, __HIP_MEMORY_SCOPE_AGENT) < t + 1) {
          __builtin_amdgcn_s_sleep(1);
          if (++spins > 2000000) { bail = true; break; }
        }
      }
      __syncthreads();
      const char* hsrc = (const char*)Hh + (size_t)(t + 1) * 32768;
#pragma unroll
      for (int rr = 0; rr < 8; ++rr) {
        const int R = v * 8 + rr;
        gload_lds16_sc(hsrc + R * 1024 + ((16 * l) ^ ((R & 7) << 4)), (char*)aL + R * 1024);
      }
      __syncthreads();
      f32x4 acc[2] = {};
#pragma unroll
      for (int kf = 0; kf < 16; ++kf)
#pragma unroll
        for (int mf = 0; mf < 2; ++mf) {
          const int row = mf * 16 + ln;
          const int byteoff = (row * 1024 + kf * 64 + q * 16) ^ ((row & 7) << 4);
          bf16x8 a = *(const bf16x8*)((const char*)aL + byteoff);
          acc[mf] = __builtin_amdgcn_mfma_f32_16x16x32_bf16(a, B[kf], acc[mf], 0, 0, 0);
        }
#pragma unroll
      for (int mf = 0; mf < 2; ++mf)
#pragma unroll
        for (int r = 0; r < 4; ++r)
          pOut[(mf * 16 + q * 4 + r) * 72 + 16 * v + ln] = f2bf(tanh_f(acc[mf][r] + crv[mf][r]));
      __syncthreads();
      {
        const int b = tid >> 3, ch = tid & 7;
        u32x4 pv = *(const u32x4*)(pOut + b * 72 + ch * 8);
        char* pp = (char*)P + (size_t)t * 32768 + b * 1024 + 128 * c + ch * 16;
        asm volatile("global_store_dwordx4 %0, %1, off sc0 sc1" :: "v"(pp), "v"(pv) : "memory");
      }
      __syncthreads();   // publish drained (vmcnt0 before barrier)
      if (tid == 0)
        __hip_atomic_store(flags + 512 + c * 32, t + 1, __ATOMIC_RELAXED, __HIP_MEMORY_SCOPE_AGENT);
    }
    return;
  }

  // ---------------- worker path (proven) ----------------
  const int w = bid;
  const int mh = v >> 1, nh = v & 1;
  ushort_t* hL = (ushort_t*)smem;
  ushort_t* hOutL = (ushort_t*)(smem + 32768);  // [32][40]

  bf16x8 WA[4][16];
#pragma unroll
  for (int mt = 0; mt < 4; ++mt)
#pragma unroll
    for (int kt = 0; kt < 16; ++kt)
      WA[mt][kt] = *(const bf16x8*)(Whh + (size_t)(128 * w + 64 * mh + mt * 16 + ln) * 512 + kt * 32 + q * 8);

  const int b = 16 * nh + ln;
  const int d0 = 32 * w + 16 * mh;
  float cst[4];
  float4 fv1[4], fv0[4];
  uint2 egc[4];
#pragma unroll
  for (int mt = 0; mt < 4; ++mt) {
    const int d = d0 + mt * 4 + q;
    cst[mt] = c_init[b * 512 + d];
    fv1[mt] = *(const float4*)(F1 + (d * 32 + b) * 4);
    fv0[mt] = *(const float4*)(F0 + (d * 32 + b) * 4);
    egc[mt] = *(const uint2*)(Eg2 + ((size_t)d * 32 + b) * 4);
  }

  bool bail = false;
  for (int t = 0; t < 64; ++t) {
    const char* hsrc = (const char*)Hh + (size_t)t * 32768;
#pragma unroll
    for (int rr = 0; rr < 8; ++rr) {
      const int R = v * 8 + rr;
      gload_lds16_sc(hsrc + R * 1024 + ((16 * l) ^ ((R & 7) << 4)), (char*)hL + R * 1024);
    }
    uint2 egn[4];
    const int tn = (t + 1) & 63;
#pragma unroll
    for (int mt = 0; mt < 4; ++mt)
      egn[mt] = *(const uint2*)(Eg2 + ((size_t)(tn * 512 + d0 + mt * 4 + q) * 32 + b) * 4);
    __syncthreads();

    f32x4 acc[4] = {};
#pragma unroll
    for (int kt = 0; kt < 16; ++kt) {
      const int byteoff = (b * 1024 + kt * 64 + q * 16) ^ ((b & 7) << 4);
      bf16x8 hv = *(const bf16x8*)((const char*)hL + byteoff);
#pragma unroll
      for (int mt = 0; mt < 4; ++mt)
        acc[mt] = __builtin_amdgcn_mfma_f32_16x16x32_bf16(WA[mt][kt], hv, acc[mt], 0, 0, 0);
    }

#pragma unroll
    for (int mt = 0; mt < 4; ++mt) {
      const float4 fv = (t == 0) ? fv0[mt] : fv1[mt];
      float gi = acc[mt][0] + bfu2f(egc[mt].x & 0xFFFFu) + fv.x;
      float gf = acc[mt][1] + bfu2f(egc[mt].x >> 16) + fv.y;
      float gg = acc[mt][2] + bfu2f(egc[mt].y & 0xFFFFu) + fv.z;
      float go = acc[mt][3] + bfu2f(egc[mt].y >> 16) + fv.w;
      float c = sigm(gf) * cst[mt] + sigm(gi) * tanh_f(gg);
      cst[mt] = c;
      hOutL[b * 40 + 16 * mh + mt * 4 + q] = f2bf(sigm(go) * tanh_f(c));
      egc[mt] = egn[mt];
    }
    __syncthreads();

    if (tid < 128) {
      const int b2 = tid >> 2, c16 = (tid & 3) * 8;
      const u32x4 val = *(const u32x4*)(hOutL + b2 * 40 + c16);
      ushort_t* hp = Hh + (size_t)(t + 1) * 16384 + b2 * 512 + 32 * w + c16;
      asm volatile("global_store_dwordx4 %0, %1, off sc0 sc1" :: "v"(hp), "v"(val) : "memory");
    }
    __syncthreads();                       // publish drained (vmcnt0 before barrier)

    if (tid == 0)
      __hip_atomic_store(flags + w * 32, t + 1, __ATOMIC_RELAXED, __HIP_MEMORY_SCOPE_AGENT);

    if (t < 63) {
      if (!bail && tid < 16) {
        int spins = 0;
        while (__hip_atomic_load(flags + tid * 32, __ATOMIC_RELAXED, __HIP_MEMORY_SCOPE_AGENT) < t + 1) {
          __builtin_amdgcn_s_sleep(1);
          if (++spins > 2000000) { bail = true; break; }
        }
      }
      __syncthreads();
    }
  }
}

// ---------- launcher ----------
extern "C" void kernel_launch(void* const* d_in, const int* in_sizes, int n_in,
                              void* d_out, int out_size, void* d_ws, size_t ws_size,
                              hipStream_t stream) {
  const float* x_enc   = (const float*)d_in[0];
  const float* x_enc_k = (const float*)d_in[1];
  const float* h0f     = (const float*)d_in[2];
  const float* c0f     = (const float*)d_in[3];
  const int*   y_train = (const int*)d_in[5];
  const float* emb     = (const float*)d_in[7];
  const float* W_ih    = (const float*)d_in[8];
  const float* W_hh    = (const float*)d_in[9];
  const float* b_ih    = (const float*)d_in[10];
  const float* b_hh    = (const float*)d_in[11];
  const float* w_att   = (const float*)d_in[14];
  const float* c2r     = (const float*)d_in[16];
  const float* Rw      = (const float*)d_in[17];
  float* out = (float*)d_out;
  char* ws = (char*)d_ws;

  int*      flags    = (int*)(ws + WS_FLAGS);
  float*    ctx      = (float*)(ws + WS_CTX);
  float*    ctxT     = (float*)(ws + WS_CTXT);
  float*    ctx_read = (float*)(ws + WS_CTXRD);
  float*    F1r      = (float*)(ws + WS_F1);
  float*    F0r      = (float*)(ws + WS_F0);
  ushort_t* Ebf      = (ushort_t*)(ws + WS_EBF);
  ushort_t* Wih      = (ushort_t*)(ws + WS_WIH);
  ushort_t* Whh      = (ushort_t*)(ws + WS_WHH);
  ushort_t* Eg2      = (ushort_t*)(ws + WS_EG);
  ushort_t* Hh       = (ushort_t*)(ws + WS_HH);
  ushort_t* P        = (ushort_t*)(ws + WS_P);

  k_pre1<<<1577, 256, 0, stream>>>(x_enc_k, x_enc, w_att, ctx, ctxT,
                                   W_ih, W_hh, h0f, emb, y_train,
                                   Wih, Whh, Hh, Ebf, flags);
  k_pre2<<<576, 256, 0, stream>>>(ctxT, W_ih, b_ih, b_hh, c2r, F1r, F0r, ctx_read,
                                  Ebf, Wih, Eg2);
  k_recur<<<149, 256, 0, stream>>>(Eg2, F1r, F0r, Whh, c0f, Hh, P, flags, c2r, ctx_read, Rw, out);
  (void)in_sizes; (void)n_in; (void)out_size; (void)ws_size;
}